// Round 4
// baseline (122.303 us; speedup 1.0000x reference)
//
#include <hip/hip_runtime.h>
#include <stdint.h>

#define B_IMG  8
#define NANCH  17328          // A*HW = 3*5776
#define NCLS   80
#define TOPK   200
#define NPART  4
#define PARTN  (NANCH / NPART)    // 4332
#define PARTN4 (PARTN / 4)        // 1083 float4s
#define NTHR   256

// ---------------------------------------------------------------------------
// K1: transpose scores [B][N][C] -> [B][C][N] so per-class reads are coalesced
// ---------------------------------------------------------------------------
__global__ __launch_bounds__(NTHR) void transpose_scores_k(
    const float* __restrict__ scores, float* __restrict__ ts) {
  __shared__ float tile[64][81];  // +1 pad: conflict-free transposed reads
  const int b = blockIdx.y;
  const int n0 = blockIdx.x * 64;
  const int tid = threadIdx.x;

  for (int f = tid; f < 64 * NCLS; f += NTHR) {
    int dn = f / NCLS, c = f - dn * NCLS;
    int n = n0 + dn;
    if (n < NANCH) tile[dn][c] = scores[((size_t)b * NANCH + n) * NCLS + c];
  }
  __syncthreads();
  for (int f = tid; f < NCLS * 64; f += NTHR) {
    int c = f >> 6, dn = f & 63;
    int n = n0 + dn;
    if (n < NANCH) ts[((size_t)b * NCLS + c) * NANCH + n] = tile[dn][c];
  }
}

// ---------------------------------------------------------------------------
// helpers
// ---------------------------------------------------------------------------
__device__ __forceinline__ void hist_add(float s, unsigned int* hist) {
  if (s > 0.5f) {
    unsigned int bin = (__float_as_uint(s) - 0x3F000000u) >> 15;
    if (bin > 255u) bin = 255u;
    atomicAdd(&hist[bin], 1u);
  }
}

__device__ __forceinline__ void compact_add(float s, int gidx, unsigned int cutbits,
                                            unsigned long long* keys, int* sh_m) {
  if (s > 0.5f && __float_as_uint(s) >= cutbits) {
    int slot = atomicAdd(sh_m, 1);
    if (slot < 512)
      keys[slot] = ((unsigned long long)__float_as_uint(s) << 32) |
                   (unsigned long long)(0xFFFFFFFFu - (unsigned int)gidx);
  }
}

// count of elements strictly greater than k in a descending 256-entry list
// (monotone predicate -> branchless bit-descent, 8 LDS reads)
__device__ __forceinline__ int cnt_gt(const unsigned long long* d, unsigned long long k) {
  int i = 0;
#pragma unroll
  for (int s = 128; s >= 1; s >>= 1)
    if (d[i + s - 1] > k) i += s;
  return i;
}

// ---------------------------------------------------------------------------
// K2 (stage 1, transposed path): SINGLE global pass per (b,c,part):
// compact all s>0.5 candidates to LDS, histogram, cutoff, select, sort, top200
// ---------------------------------------------------------------------------
__global__ __launch_bounds__(NTHR) void stage1_t_k(
    const float* __restrict__ ts, unsigned long long* __restrict__ topkeys) {
  const int blk = blockIdx.x;
  const int p = blk & (NPART - 1);
  const int bc = blk >> 2;
  const int tid = threadIdx.x;
  const int lane = tid & 63;

  __shared__ unsigned long long allk[4352];   // >= PARTN: never overflows
  __shared__ unsigned long long selk[512];
  __shared__ unsigned int hist[256];
  __shared__ unsigned int sh_cutbits;
  __shared__ int m_all, m_sel;

  for (int j = tid; j < 256; j += NTHR) hist[j] = 0;
  if (tid == 0) { m_all = 0; m_sel = 0; }
  __syncthreads();

  // ---- single pass: histogram + wave-aggregated compaction of candidates ----
  const float4* src4 = (const float4*)(ts + (size_t)bc * NANCH + (size_t)p * PARTN);
  const int gbase = p * PARTN;
  for (int i = tid; i < PARTN4; i += NTHR) {
    float4 v = src4[i];
    const int gi = gbase + 4 * i;
    float se[4] = {v.x, v.y, v.z, v.w};
#pragma unroll
    for (int e = 0; e < 4; ++e) {
      float s = se[e];
      bool cand = (s > 0.5f);
      if (cand) hist_add(s, hist);
      unsigned long long bal = __ballot(cand);
      if (bal) {
        int basePos;
        if (lane == 0) basePos = atomicAdd(&m_all, __popcll(bal));
        basePos = __shfl(basePos, 0, 64);
        if (cand) {
          int my = basePos + __popcll(bal & ((1ull << lane) - 1ull));
          allk[my] = ((unsigned long long)__float_as_uint(s) << 32) |
                     (unsigned long long)(0xFFFFFFFFu - (unsigned int)(gi + e));
        }
      }
    }
  }
  __syncthreads();

  // ---- wave-parallel cutoff: smallest bin with >=200 items at/above it ----
  if (tid < 64) {
    int base = 255 - 4 * tid;
    int s4 = (int)(hist[base] + hist[base - 1] + hist[base - 2] + hist[base - 3]);
    int cum = s4;
    for (int d = 1; d < 64; d <<= 1) {
      int o = __shfl_up(cum, d, 64);
      if (tid >= d) cum += o;
    }
    unsigned long long bal = __ballot(cum >= TOPK);
    if (bal == 0ull) {
      if (tid == 0) sh_cutbits = 0x3F000000u;  // take every candidate
    } else {
      int l0 = __builtin_ctzll(bal);
      if (tid == l0) {
        unsigned int acc = (unsigned int)(cum - s4);
        int cutbin = base - 3;
        for (int k = 0; k < 4; ++k) {
          acc += hist[base - k];
          if (acc >= TOPK) { cutbin = base - k; break; }
        }
        sh_cutbits = 0x3F000000u + ((unsigned int)cutbin << 15);
      }
    }
  }
  __syncthreads();
  const unsigned int cutbits = sh_cutbits;

  // ---- select from LDS (same set as the old 2nd global pass) --------------
  const int Mall = m_all;
  for (int j = tid; j < Mall; j += NTHR) {
    unsigned long long k = allk[j];
    if ((unsigned int)(k >> 32) >= cutbits) {
      int slot = atomicAdd(&m_sel, 1);
      if (slot < 512) selk[slot] = k;
    }
  }
  __syncthreads();

  int M = m_sel; if (M > 512) M = 512;
  const int S = (M <= 256) ? 256 : 512;
  for (int j = M + tid; j < S; j += NTHR) selk[j] = 0ull;

  // ---- bitonic sort S elements, descending ----
  for (int size = 2; size <= S; size <<= 1) {
    for (int st = size >> 1; st > 0; st >>= 1) {
      __syncthreads();
      for (int t = tid; t < (S >> 1); t += NTHR) {
        int lo = 2 * t - (t & (st - 1));
        int hi = lo + st;
        bool desc = ((lo & size) == 0);
        unsigned long long a = selk[lo], bb = selk[hi];
        if ((a < bb) == desc) { selk[lo] = bb; selk[hi] = a; }
      }
    }
  }
  __syncthreads();

  if (tid < TOPK) topkeys[(size_t)blk * TOPK + tid] = selk[tid];
}

// ---------------------------------------------------------------------------
// K2b (stage 1 fallback, non-transposed strided reads) — proven, 2 passes
// ---------------------------------------------------------------------------
__global__ __launch_bounds__(NTHR) void stage1_k(
    const float* __restrict__ scores, unsigned long long* __restrict__ topkeys) {
  const int blk = blockIdx.x;
  const int p = blk & (NPART - 1);
  const int bc = blk >> 2;
  const int b = bc / NCLS;
  const int c = bc - b * NCLS;
  const int tid = threadIdx.x;

  __shared__ unsigned int hist[256];
  __shared__ unsigned long long keys[512];
  __shared__ unsigned int sh_cutbits;
  __shared__ int sh_m;

  for (int j = tid; j < 256; j += NTHR) hist[j] = 0;
  if (tid == 0) sh_m = 0;
  __syncthreads();

  const float* src = scores + ((size_t)b * NANCH + (size_t)p * PARTN) * NCLS + c;
  for (int i = tid; i < PARTN; i += NTHR) hist_add(src[(size_t)i * NCLS], hist);
  __syncthreads();

  if (tid < 64) {
    int base = 255 - 4 * tid;
    int s4 = (int)(hist[base] + hist[base - 1] + hist[base - 2] + hist[base - 3]);
    int cum = s4;
    for (int d = 1; d < 64; d <<= 1) {
      int o = __shfl_up(cum, d, 64);
      if (tid >= d) cum += o;
    }
    unsigned long long bal = __ballot(cum >= TOPK);
    if (bal == 0ull) {
      if (tid == 0) sh_cutbits = 0x3F000000u;
    } else {
      int l0 = __builtin_ctzll(bal);
      if (tid == l0) {
        unsigned int acc = (unsigned int)(cum - s4);
        int cutbin = base - 3;
        for (int k = 0; k < 4; ++k) {
          acc += hist[base - k];
          if (acc >= TOPK) { cutbin = base - k; break; }
        }
        sh_cutbits = 0x3F000000u + ((unsigned int)cutbin << 15);
      }
    }
  }
  __syncthreads();
  const unsigned int cutbits = sh_cutbits;

  const int gbase = p * PARTN;
  for (int i = tid; i < PARTN; i += NTHR)
    compact_add(src[(size_t)i * NCLS], gbase + i, cutbits, keys, &sh_m);
  __syncthreads();

  int M = sh_m; if (M > 512) M = 512;
  const int S = (M <= 256) ? 256 : 512;
  for (int j = M + tid; j < S; j += NTHR) keys[j] = 0ull;

  for (int size = 2; size <= S; size <<= 1) {
    for (int st = size >> 1; st > 0; st >>= 1) {
      __syncthreads();
      for (int t = tid; t < (S >> 1); t += NTHR) {
        int lo = 2 * t - (t & (st - 1));
        int hi = lo + st;
        bool desc = ((lo & size) == 0);
        unsigned long long a = keys[lo], bb = keys[hi];
        if ((a < bb) == desc) { keys[lo] = bb; keys[hi] = a; }
      }
    }
  }
  __syncthreads();

  if (tid < TOPK) topkeys[(size_t)blk * TOPK + tid] = keys[tid];
}

// ---------------------------------------------------------------------------
// K3 (stage 2): RANK-MERGE 4 sorted lists -> exact top-200, bitmask NMS, emit
// ---------------------------------------------------------------------------
__global__ __launch_bounds__(NTHR) void stage2_k(
    const float* __restrict__ boxes, const unsigned long long* __restrict__ topkeys,
    float* __restrict__ out) {
  const int bc = blockIdx.x;
  const int b = bc / NCLS;
  const int c = bc - b * NCLS;
  const int tid = threadIdx.x;

  __shared__ __align__(16) unsigned long long lists[NPART][256];  // desc, 0-pad
  __shared__ __align__(16) unsigned long long outk[256];
  __shared__ float sx1[256], sy1[256], sx2[256], sy2[256], sar[256], ssc[256];
  __shared__ int skeep[256];
  __shared__ __align__(16) unsigned long long sup[TOPK][4];   // 6.4 KB

  // zero lists (incl. padding) and outk
  for (int f = tid; f < NPART * 256; f += NTHR) ((unsigned long long*)lists)[f] = 0ull;
  outk[tid] = 0ull;
  __syncthreads();

  const unsigned long long* tk = topkeys + (size_t)bc * (NPART * TOPK);
  for (int f = tid; f < NPART * TOPK; f += NTHR) {
    int p = f / TOPK, j = f - p * TOPK;
    lists[p][j] = tk[f];
  }
  __syncthreads();

  // ---- rank each key among the union; scatter top-200 directly ------------
  // keys are globally distinct (distinct idx) -> ranks unique -> no conflicts
  for (int f = tid; f < NPART * TOPK; f += NTHR) {
    int p = f / TOPK, j = f - p * TOPK;
    unsigned long long k = lists[p][j];
    if (k != 0ull) {
      int r = j;
#pragma unroll
      for (int q = 0; q < NPART; ++q)
        if (q != p) r += cnt_gt(lists[q], k);
      if (r < TOPK) outk[r] = k;
    }
  }
  __syncthreads();

  // ---- gather top-200 boxes (slots 200..255 zero) --------------------------
  {
    unsigned long long key = outk[tid];
    int valid = (tid < TOPK) && (key != 0ull);
    float sc = __uint_as_float((unsigned int)(key >> 32));
    unsigned int idx = 0xFFFFFFFFu - (unsigned int)(key & 0xFFFFFFFFull);
    float4 bx = make_float4(0.f, 0.f, 0.f, 0.f);
    if (valid) bx = ((const float4*)boxes)[(size_t)b * NANCH + idx];
    sx1[tid] = bx.x; sy1[tid] = bx.y; sx2[tid] = bx.z; sy2[tid] = bx.w;
    sar[tid] = __fmul_rn(bx.z - bx.x, bx.w - bx.y);   // _rn: block FMA contraction
    ssc[tid] = valid ? sc : 0.f;
    skeep[tid] = valid;
  }
  __syncthreads();

  // ---- parallel suppression-matrix build (upper triangle) -----------------
  {
    const int wv = tid >> 6, lane = tid & 63;
    float jx1[4], jy1[4], jx2[4], jy2[4], ja[4];
#pragma unroll
    for (int r = 0; r < 4; ++r) {
      int j = (r << 6) | lane;
      jx1[r] = sx1[j]; jy1[r] = sy1[j]; jx2[r] = sx2[j]; jy2[r] = sy2[j];
      ja[r] = sar[j];
    }
    for (int i = wv; i < TOPK; i += 4) {
      const float xi1 = sx1[i], yi1 = sy1[i], xi2 = sx2[i], yi2 = sy2[i];
      const float ai = sar[i];
#pragma unroll
      for (int r = 0; r < 4; ++r) {
        unsigned long long word = 0ull;
        if ((r << 6) + 63 > i) {            // wave-uniform: block has some j > i
          const int j = (r << 6) | lane;
          bool s = false;
          if (j > i && j < TOPK) {
            float xx1 = fmaxf(xi1, jx1[r]);
            float yy1 = fmaxf(yi1, jy1[r]);
            float xx2 = fminf(xi2, jx2[r]);
            float yy2 = fminf(yi2, jy2[r]);
            float iw = fmaxf(0.f, __fsub_rn(xx2, xx1));
            float ih = fmaxf(0.f, __fsub_rn(yy2, yy1));
            float inter = __fmul_rn(iw, ih);
            float denom = __fsub_rn(__fadd_rn(ai, ja[r]), inter);
            // fast approx decision; exact IEEE div only inside the guard band
            float q = __fmul_rn(inter, __builtin_amdgcn_rcpf(denom));
            s = q > 0.5f;
            if (fabsf(q - 0.5f) < 1e-5f)
              s = __fdiv_rn(inter, denom) > 0.5f;   // bitwise-matches XLA
          }
          word = __ballot(s);
        }
        if (lane == 0) sup[i][r] = word;
      }
    }
  }
  __syncthreads();

  // ---- serial scan: pure bit-ops, keep state in 4 u64 regs (wave 0) -------
  if (tid < 64) {
    unsigned long long k0 = __ballot(skeep[tid] != 0);
    unsigned long long k1 = __ballot(skeep[64 + tid] != 0);
    unsigned long long k2 = __ballot(skeep[128 + tid] != 0);
    unsigned long long k3 = __ballot(skeep[192 + tid] != 0);  // 200..255 are 0
#define NMS_SCAN_WORD(KW, BASE, CNT)                                     \
    _Pragma("unroll 8")                                                  \
    for (int li = 0; li < (CNT); ++li) {                                 \
      const ulonglong2* s2p =                                            \
          reinterpret_cast<const ulonglong2*>(&sup[(BASE) + li][0]);     \
      ulonglong2 sa = s2p[0];                                            \
      ulonglong2 sb = s2p[1];                                            \
      unsigned long long m = 0ull - ((KW >> li) & 1ull);                 \
      k0 &= ~(sa.x & m); k1 &= ~(sa.y & m);                              \
      k2 &= ~(sb.x & m); k3 &= ~(sb.y & m);                              \
    }
    NMS_SCAN_WORD(k0, 0, 64)
    NMS_SCAN_WORD(k1, 64, 64)
    NMS_SCAN_WORD(k2, 128, 64)
    NMS_SCAN_WORD(k3, 192, 8)
#undef NMS_SCAN_WORD
    skeep[tid]        = (int)((k0 >> tid) & 1ull);
    skeep[64 + tid]   = (int)((k1 >> tid) & 1ull);
    skeep[128 + tid]  = (int)((k2 >> tid) & 1ull);
    skeep[192 + tid]  = (int)((k3 >> tid) & 1ull);
  }
  __syncthreads();

  // ---- emit (box4, score, class) rows, zeroed where not kept -------------
  const size_t base = ((size_t)b * NCLS + c) * (TOPK * 6);
  for (int f = tid; f < TOPK * 6; f += NTHR) {
    int k = f / 6, comp = f - k * 6;
    float v = 0.f;
    if (skeep[k]) {
      switch (comp) {
        case 0: v = sx1[k]; break;
        case 1: v = sy1[k]; break;
        case 2: v = sx2[k]; break;
        case 3: v = sy2[k]; break;
        case 4: v = ssc[k]; break;
        default: v = (float)c; break;
      }
    }
    out[base + f] = v;
  }
}

// ---------------------------------------------------------------------------
// Fallback: proven monolithic kernel (strided reads), used only if ws tiny
// ---------------------------------------------------------------------------
__global__ __launch_bounds__(NTHR) void select_nms_k(
    const float* __restrict__ boxes, const float* __restrict__ scores,
    float* __restrict__ out) {
  const int blk = blockIdx.x;
  const int b = blk / NCLS;
  const int c = blk - b * NCLS;
  const int tid = threadIdx.x;

  __shared__ unsigned int hist[256];
  __shared__ unsigned long long keys[1024];
  __shared__ float sx1[TOPK], sy1[TOPK], sx2[TOPK], sy2[TOPK], sar[TOPK], ssc[TOPK];
  __shared__ int skeep[TOPK];
  __shared__ unsigned int sh_cutbits;
  __shared__ int sh_m;

  const float* src = scores + (size_t)b * NANCH * NCLS + c;

  for (int j = tid; j < 256; j += NTHR) hist[j] = 0;
  if (tid == 0) sh_m = 0;
  __syncthreads();

  for (int i = tid; i < NANCH; i += NTHR) hist_add(src[(size_t)i * NCLS], hist);
  __syncthreads();

  if (tid == 0) {
    unsigned int acc = 0;
    int cut = 0;
    for (int bin = 255; bin >= 0; --bin) {
      acc += hist[bin];
      if (acc >= TOPK) { cut = bin; break; }
    }
    sh_cutbits = 0x3F000000u + ((unsigned int)cut << 15);
  }
  __syncthreads();
  const unsigned int cutbits = sh_cutbits;

  for (int i = tid; i < NANCH; i += NTHR) {
    float s = src[(size_t)i * NCLS];
    if (s > 0.5f && __float_as_uint(s) >= cutbits) {
      int slot = atomicAdd(&sh_m, 1);
      if (slot < 1024)
        keys[slot] = ((unsigned long long)__float_as_uint(s) << 32) |
                     (unsigned long long)(0xFFFFFFFFu - (unsigned int)i);
    }
  }
  __syncthreads();
  int M = sh_m; if (M > 1024) M = 1024;
  for (int j = M + tid; j < 1024; j += NTHR) keys[j] = 0ull;

  for (int size = 2; size <= 1024; size <<= 1) {
    for (int st = size >> 1; st > 0; st >>= 1) {
      __syncthreads();
      for (int t = tid; t < 512; t += NTHR) {
        int lo = 2 * t - (t & (st - 1));
        int hi = lo + st;
        bool desc = ((lo & size) == 0);
        unsigned long long a = keys[lo], bb = keys[hi];
        if ((a < bb) == desc) { keys[lo] = bb; keys[hi] = a; }
      }
    }
  }
  __syncthreads();

  if (tid < TOPK) {
    unsigned long long key = keys[tid];
    int valid = (key != 0ull);
    float sc = __uint_as_float((unsigned int)(key >> 32));
    unsigned int idx = 0xFFFFFFFFu - (unsigned int)(key & 0xFFFFFFFFull);
    float4 bx = make_float4(0.f, 0.f, 0.f, 0.f);
    if (valid) bx = ((const float4*)boxes)[(size_t)b * NANCH + idx];
    sx1[tid] = bx.x; sy1[tid] = bx.y; sx2[tid] = bx.z; sy2[tid] = bx.w;
    sar[tid] = __fmul_rn(bx.z - bx.x, bx.w - bx.y);
    ssc[tid] = valid ? sc : 0.f;
    skeep[tid] = valid;
  }
  __syncthreads();

  if (tid < 64) {
    const int lane = tid;
    float x1v[4], y1v[4], x2v[4], y2v[4], av[4];
    int km = 0;
#pragma unroll
    for (int r = 0; r < 4; ++r) {
      int j = lane + (r << 6);
      if (j < TOPK) {
        x1v[r] = sx1[j]; y1v[r] = sy1[j]; x2v[r] = sx2[j]; y2v[r] = sy2[j];
        av[r] = sar[j];
        if (skeep[j]) km |= (1 << r);
      } else {
        x1v[r] = 0.f; y1v[r] = 0.f; x2v[r] = 0.f; y2v[r] = 0.f; av[r] = 0.f;
      }
    }
#pragma unroll
    for (int ri = 0; ri < 4; ++ri) {
      const int imax = (ri == 3) ? (TOPK - 192) : 64;
      for (int li = 0; li < imax; ++li) {
        const int i = (ri << 6) + li;
        int kmi = __shfl(km, li, 64);
        if (!((kmi >> ri) & 1)) continue;
        float xi1 = __shfl(x1v[ri], li, 64);
        float yi1 = __shfl(y1v[ri], li, 64);
        float xi2 = __shfl(x2v[ri], li, 64);
        float yi2 = __shfl(y2v[ri], li, 64);
        float ai  = __shfl(av[ri],  li, 64);
#pragma unroll
        for (int r = 0; r < 4; ++r) {
          int j = lane + (r << 6);
          if (j > i && j < TOPK && ((km >> r) & 1)) {
            float xx1 = fmaxf(xi1, x1v[r]);
            float yy1 = fmaxf(yi1, y1v[r]);
            float xx2 = fminf(xi2, x2v[r]);
            float yy2 = fminf(yi2, y2v[r]);
            float iw = fmaxf(0.f, __fsub_rn(xx2, xx1));
            float ih = fmaxf(0.f, __fsub_rn(yy2, yy1));
            float inter = __fmul_rn(iw, ih);
            float denom = __fsub_rn(__fadd_rn(ai, av[r]), inter);
            float iou = __fdiv_rn(inter, denom);
            if (iou > 0.5f) km &= ~(1 << r);
          }
        }
      }
    }
#pragma unroll
    for (int r = 0; r < 4; ++r) {
      int j = lane + (r << 6);
      if (j < TOPK) skeep[j] = (km >> r) & 1;
    }
  }
  __syncthreads();

  const size_t base = ((size_t)b * NCLS + c) * (TOPK * 6);
  for (int f = tid; f < TOPK * 6; f += NTHR) {
    int k = f / 6, comp = f - k * 6;
    float v = 0.f;
    if (skeep[k]) {
      switch (comp) {
        case 0: v = sx1[k]; break;
        case 1: v = sy1[k]; break;
        case 2: v = sx2[k]; break;
        case 3: v = sy2[k]; break;
        case 4: v = ssc[k]; break;
        default: v = (float)c; break;
      }
    }
    out[base + f] = v;
  }
}

// ---------------------------------------------------------------------------
extern "C" void kernel_launch(void* const* d_in, const int* in_sizes, int n_in,
                              void* d_out, int out_size, void* d_ws, size_t ws_size,
                              hipStream_t stream) {
  (void)in_sizes; (void)n_in; (void)out_size;
  const float* boxes  = (const float*)d_in[0];
  const float* scores = (const float*)d_in[1];
  float* out = (float*)d_out;

  const size_t need_ts = (size_t)B_IMG * NCLS * NANCH * sizeof(float);             // 44.4 MB
  const size_t need_tk = (size_t)B_IMG * NCLS * NPART * TOPK * sizeof(uint64_t);   // 4.1 MB

  if (ws_size >= need_ts + need_tk) {
    float* ts = (float*)d_ws;
    unsigned long long* topkeys = (unsigned long long*)((char*)d_ws + need_ts);
    dim3 tgrid((NANCH + 63) / 64, B_IMG);
    transpose_scores_k<<<tgrid, NTHR, 0, stream>>>(scores, ts);
    stage1_t_k<<<B_IMG * NCLS * NPART, NTHR, 0, stream>>>(ts, topkeys);
    stage2_k<<<B_IMG * NCLS, NTHR, 0, stream>>>(boxes, topkeys, out);
  } else if (ws_size >= need_tk) {
    unsigned long long* topkeys = (unsigned long long*)d_ws;
    stage1_k<<<B_IMG * NCLS * NPART, NTHR, 0, stream>>>(scores, topkeys);
    stage2_k<<<B_IMG * NCLS, NTHR, 0, stream>>>(boxes, topkeys, out);
  } else {
    select_nms_k<<<B_IMG * NCLS, NTHR, 0, stream>>>(boxes, scores, out);
  }
}

// Round 5
// 110.978 us; speedup vs baseline: 1.1021x; 1.1021x over previous
//
#include <hip/hip_runtime.h>
#include <stdint.h>

#define B_IMG  8
#define NANCH  17328          // A*HW = 3*5776
#define NCLS   80
#define TOPK   200
#define NPART  4
#define PARTN  (NANCH / NPART)    // 4332
#define PARTN4 (PARTN / 4)        // 1083 float4s
#define NTHR   256

// ---------------------------------------------------------------------------
// K1: transpose scores [B][N][C] -> [B][C][N] so per-class reads are coalesced
// ---------------------------------------------------------------------------
__global__ __launch_bounds__(NTHR) void transpose_scores_k(
    const float* __restrict__ scores, float* __restrict__ ts) {
  __shared__ float tile[64][81];  // +1 pad: conflict-free transposed reads
  const int b = blockIdx.y;
  const int n0 = blockIdx.x * 64;
  const int tid = threadIdx.x;

  for (int f = tid; f < 64 * NCLS; f += NTHR) {
    int dn = f / NCLS, c = f - dn * NCLS;
    int n = n0 + dn;
    if (n < NANCH) tile[dn][c] = scores[((size_t)b * NANCH + n) * NCLS + c];
  }
  __syncthreads();
  for (int f = tid; f < NCLS * 64; f += NTHR) {
    int c = f >> 6, dn = f & 63;
    int n = n0 + dn;
    if (n < NANCH) ts[((size_t)b * NCLS + c) * NANCH + n] = tile[dn][c];
  }
}

// ---------------------------------------------------------------------------
// helpers
// ---------------------------------------------------------------------------
__device__ __forceinline__ void hist_add(float s, unsigned int* hist) {
  if (s > 0.5f) {
    unsigned int bin = (__float_as_uint(s) - 0x3F000000u) >> 15;
    if (bin > 255u) bin = 255u;
    atomicAdd(&hist[bin], 1u);
  }
}

__device__ __forceinline__ void compact_add(float s, int gidx, unsigned int cutbits,
                                            unsigned long long* keys, int* sh_m) {
  if (s > 0.5f && __float_as_uint(s) >= cutbits) {
    int slot = atomicAdd(sh_m, 1);
    if (slot < 512)
      keys[slot] = ((unsigned long long)__float_as_uint(s) << 32) |
                   (unsigned long long)(0xFFFFFFFFu - (unsigned int)gidx);
  }
}

// count of elements strictly greater than k in a descending 256-entry list
__device__ __forceinline__ int cnt_gt(const unsigned long long* d, unsigned long long k) {
  int i = 0;
#pragma unroll
  for (int s = 128; s >= 1; s >>= 1)
    if (d[i + s - 1] > k) i += s;
  return i;
}

// ---------------------------------------------------------------------------
// K2 (stage 1): per-(b,c,part) exact top-200 keys -> global ws  (rd3-proven)
// blk = (b*NCLS + c)*NPART + p
// ---------------------------------------------------------------------------
__global__ __launch_bounds__(NTHR) void stage1_k(
    const float* __restrict__ scores, const float* __restrict__ ts, int use_t,
    unsigned long long* __restrict__ topkeys) {
  const int blk = blockIdx.x;
  const int p = blk & (NPART - 1);
  const int bc = blk >> 2;
  const int b = bc / NCLS;
  const int c = bc - b * NCLS;
  const int tid = threadIdx.x;

  __shared__ unsigned int hist[256];
  __shared__ unsigned long long keys[512];
  __shared__ unsigned int sh_cutbits;
  __shared__ int sh_m;

  for (int j = tid; j < 256; j += NTHR) hist[j] = 0;
  if (tid == 0) sh_m = 0;
  __syncthreads();

  // ---- pass 1: histogram ----
  if (use_t) {
    const float4* src4 = (const float4*)(ts + (size_t)bc * NANCH + (size_t)p * PARTN);
    for (int i = tid; i < PARTN4; i += NTHR) {
      float4 v = src4[i];
      hist_add(v.x, hist); hist_add(v.y, hist);
      hist_add(v.z, hist); hist_add(v.w, hist);
    }
  } else {
    const float* src = scores + ((size_t)b * NANCH + (size_t)p * PARTN) * NCLS + c;
    for (int i = tid; i < PARTN; i += NTHR) hist_add(src[(size_t)i * NCLS], hist);
  }
  __syncthreads();

  // ---- wave-parallel cutoff: smallest bin with >=200 items at/above it ----
  if (tid < 64) {
    int base = 255 - 4 * tid;
    int s4 = (int)(hist[base] + hist[base - 1] + hist[base - 2] + hist[base - 3]);
    int cum = s4;
    for (int d = 1; d < 64; d <<= 1) {
      int o = __shfl_up(cum, d, 64);
      if (tid >= d) cum += o;
    }
    unsigned long long bal = __ballot(cum >= TOPK);
    if (bal == 0ull) {
      if (tid == 0) sh_cutbits = 0x3F000000u;  // take every candidate
    } else {
      int l0 = __builtin_ctzll(bal);
      if (tid == l0) {
        unsigned int acc = (unsigned int)(cum - s4);
        int cutbin = base - 3;
        for (int k = 0; k < 4; ++k) {
          acc += hist[base - k];
          if (acc >= TOPK) { cutbin = base - k; break; }
        }
        sh_cutbits = 0x3F000000u + ((unsigned int)cutbin << 15);
      }
    }
  }
  __syncthreads();
  const unsigned int cutbits = sh_cutbits;

  // ---- pass 2: compact candidate keys ----
  const int gbase = p * PARTN;
  if (use_t) {
    const float4* src4 = (const float4*)(ts + (size_t)bc * NANCH + (size_t)p * PARTN);
    for (int i = tid; i < PARTN4; i += NTHR) {
      float4 v = src4[i];
      int gi = gbase + 4 * i;
      compact_add(v.x, gi,     cutbits, keys, &sh_m);
      compact_add(v.y, gi + 1, cutbits, keys, &sh_m);
      compact_add(v.z, gi + 2, cutbits, keys, &sh_m);
      compact_add(v.w, gi + 3, cutbits, keys, &sh_m);
    }
  } else {
    const float* src = scores + ((size_t)b * NANCH + (size_t)p * PARTN) * NCLS + c;
    for (int i = tid; i < PARTN; i += NTHR)
      compact_add(src[(size_t)i * NCLS], gbase + i, cutbits, keys, &sh_m);
  }
  __syncthreads();

  int M = sh_m; if (M > 512) M = 512;
  const int S = (M <= 256) ? 256 : 512;
  for (int j = M + tid; j < S; j += NTHR) keys[j] = 0ull;

  // ---- bitonic sort S elements, descending ----
  for (int size = 2; size <= S; size <<= 1) {
    for (int st = size >> 1; st > 0; st >>= 1) {
      __syncthreads();
      for (int t = tid; t < (S >> 1); t += NTHR) {
        int lo = 2 * t - (t & (st - 1));
        int hi = lo + st;
        bool desc = ((lo & size) == 0);
        unsigned long long a = keys[lo], bb = keys[hi];
        if ((a < bb) == desc) { keys[lo] = bb; keys[hi] = a; }
      }
    }
  }
  __syncthreads();

  if (tid < TOPK) topkeys[(size_t)blk * TOPK + tid] = keys[tid];
}

// ---------------------------------------------------------------------------
// K3a (stage 2a): rank-merge 4 sorted lists -> top-200, gather boxes,
// write staged (box4, key) records to ws
// ---------------------------------------------------------------------------
__global__ __launch_bounds__(NTHR) void stage2a_k(
    const float* __restrict__ boxes, const unsigned long long* __restrict__ topkeys,
    float4* __restrict__ stagedBox, unsigned long long* __restrict__ stagedKey) {
  const int bc = blockIdx.x;
  const int b = bc / NCLS;
  const int tid = threadIdx.x;

  __shared__ __align__(16) unsigned long long lists[NPART][256];  // desc, 0-pad
  __shared__ __align__(16) unsigned long long outk[256];

  for (int f = tid; f < NPART * 256; f += NTHR) ((unsigned long long*)lists)[f] = 0ull;
  outk[tid] = 0ull;
  __syncthreads();

  const unsigned long long* tk = topkeys + (size_t)bc * (NPART * TOPK);
  for (int f = tid; f < NPART * TOPK; f += NTHR) {
    int p = f / TOPK, j = f - p * TOPK;
    lists[p][j] = tk[f];
  }
  __syncthreads();

  // rank each key among the union; keys globally distinct -> unique ranks
  for (int f = tid; f < NPART * TOPK; f += NTHR) {
    int p = f / TOPK, j = f - p * TOPK;
    unsigned long long k = lists[p][j];
    if (k != 0ull) {
      int r = j;
#pragma unroll
      for (int q = 0; q < NPART; ++q)
        if (q != p) r += cnt_gt(lists[q], k);
      if (r < TOPK) outk[r] = k;
    }
  }
  __syncthreads();

  // gather boxes for the top-200, write staged records (coalesced)
  {
    unsigned long long key = outk[tid];
    int valid = (tid < TOPK) && (key != 0ull);
    unsigned int idx = 0xFFFFFFFFu - (unsigned int)(key & 0xFFFFFFFFull);
    float4 bx = make_float4(0.f, 0.f, 0.f, 0.f);
    if (valid) bx = ((const float4*)boxes)[(size_t)b * NANCH + idx];
    stagedBox[(size_t)bc * 256 + tid] = bx;
    stagedKey[(size_t)bc * 256 + tid] = key;
  }
}

// ---------------------------------------------------------------------------
// K3b (stage 2b): 8 waves; sup-build (i-stride 8) + bit scan + emit
// ---------------------------------------------------------------------------
__global__ __launch_bounds__(512) void stage2b_k(
    const float4* __restrict__ stagedBox, const unsigned long long* __restrict__ stagedKey,
    float* __restrict__ out) {
  const int bc = blockIdx.x;
  const int c = bc - (bc / NCLS) * NCLS;
  const int tid = threadIdx.x;

  __shared__ float sx1[256], sy1[256], sx2[256], sy2[256], sar[256], ssc[256];
  __shared__ int skeep[256];
  __shared__ __align__(16) unsigned long long sup[TOPK][4];   // 6.4 KB

  // ---- load staged records; recompute area/score from identical bits ------
  if (tid < 256) {
    unsigned long long key = stagedKey[(size_t)bc * 256 + tid];
    float4 bx = stagedBox[(size_t)bc * 256 + tid];
    int valid = (tid < TOPK) && (key != 0ull);
    float sc = __uint_as_float((unsigned int)(key >> 32));
    sx1[tid] = bx.x; sy1[tid] = bx.y; sx2[tid] = bx.z; sy2[tid] = bx.w;
    sar[tid] = __fmul_rn(bx.z - bx.x, bx.w - bx.y);   // _rn: block FMA contraction
    ssc[tid] = valid ? sc : 0.f;
    skeep[tid] = valid;
  }
  __syncthreads();

  // ---- parallel suppression-matrix build (upper triangle), 8 waves --------
  {
    const int wv = tid >> 6, lane = tid & 63;
    float jx1[4], jy1[4], jx2[4], jy2[4], ja[4];
#pragma unroll
    for (int r = 0; r < 4; ++r) {
      int j = (r << 6) | lane;
      jx1[r] = sx1[j]; jy1[r] = sy1[j]; jx2[r] = sx2[j]; jy2[r] = sy2[j];
      ja[r] = sar[j];
    }
    for (int i = wv; i < TOPK; i += 8) {
      const float xi1 = sx1[i], yi1 = sy1[i], xi2 = sx2[i], yi2 = sy2[i];
      const float ai = sar[i];
#pragma unroll
      for (int r = 0; r < 4; ++r) {
        unsigned long long word = 0ull;
        if ((r << 6) + 63 > i) {            // wave-uniform: block has some j > i
          const int j = (r << 6) | lane;
          bool s = false;
          if (j > i && j < TOPK) {
            float xx1 = fmaxf(xi1, jx1[r]);
            float yy1 = fmaxf(yi1, jy1[r]);
            float xx2 = fminf(xi2, jx2[r]);
            float yy2 = fminf(yi2, jy2[r]);
            float iw = fmaxf(0.f, __fsub_rn(xx2, xx1));
            float ih = fmaxf(0.f, __fsub_rn(yy2, yy1));
            float inter = __fmul_rn(iw, ih);
            float denom = __fsub_rn(__fadd_rn(ai, ja[r]), inter);
            // fast approx decision; exact IEEE div only inside the guard band
            float q = __fmul_rn(inter, __builtin_amdgcn_rcpf(denom));
            s = q > 0.5f;
            if (fabsf(q - 0.5f) < 1e-5f)
              s = __fdiv_rn(inter, denom) > 0.5f;   // bitwise-matches XLA
          }
          word = __ballot(s);
        }
        if (lane == 0) sup[i][r] = word;
      }
    }
  }
  __syncthreads();

  // ---- serial scan: pure bit-ops, keep state in 4 u64 regs (wave 0) -------
  if (tid < 64) {
    unsigned long long k0 = __ballot(skeep[tid] != 0);
    unsigned long long k1 = __ballot(skeep[64 + tid] != 0);
    unsigned long long k2 = __ballot(skeep[128 + tid] != 0);
    unsigned long long k3 = __ballot(skeep[192 + tid] != 0);  // 200..255 are 0
#define NMS_SCAN_WORD(KW, BASE, CNT)                                     \
    _Pragma("unroll 8")                                                  \
    for (int li = 0; li < (CNT); ++li) {                                 \
      const ulonglong2* s2p =                                            \
          reinterpret_cast<const ulonglong2*>(&sup[(BASE) + li][0]);     \
      ulonglong2 sa = s2p[0];                                            \
      ulonglong2 sb = s2p[1];                                            \
      unsigned long long m = 0ull - ((KW >> li) & 1ull);                 \
      k0 &= ~(sa.x & m); k1 &= ~(sa.y & m);                              \
      k2 &= ~(sb.x & m); k3 &= ~(sb.y & m);                              \
    }
    NMS_SCAN_WORD(k0, 0, 64)
    NMS_SCAN_WORD(k1, 64, 64)
    NMS_SCAN_WORD(k2, 128, 64)
    NMS_SCAN_WORD(k3, 192, 8)
#undef NMS_SCAN_WORD
    skeep[tid]        = (int)((k0 >> tid) & 1ull);
    skeep[64 + tid]   = (int)((k1 >> tid) & 1ull);
    skeep[128 + tid]  = (int)((k2 >> tid) & 1ull);
    skeep[192 + tid]  = (int)((k3 >> tid) & 1ull);
  }
  __syncthreads();

  // ---- emit (box4, score, class) rows, zeroed where not kept -------------
  const size_t base = (size_t)bc * (TOPK * 6);
  for (int f = tid; f < TOPK * 6; f += 512) {
    int k = f / 6, comp = f - k * 6;
    float v = 0.f;
    if (skeep[k]) {
      switch (comp) {
        case 0: v = sx1[k]; break;
        case 1: v = sy1[k]; break;
        case 2: v = sx2[k]; break;
        case 3: v = sy2[k]; break;
        case 4: v = ssc[k]; break;
        default: v = (float)c; break;
      }
    }
    out[base + f] = v;
  }
}

// ---------------------------------------------------------------------------
// K3-full (fallback): rd4's combined rank-merge + NMS + emit
// ---------------------------------------------------------------------------
__global__ __launch_bounds__(NTHR) void stage2_full_k(
    const float* __restrict__ boxes, const unsigned long long* __restrict__ topkeys,
    float* __restrict__ out) {
  const int bc = blockIdx.x;
  const int b = bc / NCLS;
  const int c = bc - b * NCLS;
  const int tid = threadIdx.x;

  __shared__ __align__(16) unsigned long long lists[NPART][256];
  __shared__ __align__(16) unsigned long long outk[256];
  __shared__ float sx1[256], sy1[256], sx2[256], sy2[256], sar[256], ssc[256];
  __shared__ int skeep[256];
  __shared__ __align__(16) unsigned long long sup[TOPK][4];

  for (int f = tid; f < NPART * 256; f += NTHR) ((unsigned long long*)lists)[f] = 0ull;
  outk[tid] = 0ull;
  __syncthreads();

  const unsigned long long* tk = topkeys + (size_t)bc * (NPART * TOPK);
  for (int f = tid; f < NPART * TOPK; f += NTHR) {
    int p = f / TOPK, j = f - p * TOPK;
    lists[p][j] = tk[f];
  }
  __syncthreads();

  for (int f = tid; f < NPART * TOPK; f += NTHR) {
    int p = f / TOPK, j = f - p * TOPK;
    unsigned long long k = lists[p][j];
    if (k != 0ull) {
      int r = j;
#pragma unroll
      for (int q = 0; q < NPART; ++q)
        if (q != p) r += cnt_gt(lists[q], k);
      if (r < TOPK) outk[r] = k;
    }
  }
  __syncthreads();

  {
    unsigned long long key = outk[tid];
    int valid = (tid < TOPK) && (key != 0ull);
    float sc = __uint_as_float((unsigned int)(key >> 32));
    unsigned int idx = 0xFFFFFFFFu - (unsigned int)(key & 0xFFFFFFFFull);
    float4 bx = make_float4(0.f, 0.f, 0.f, 0.f);
    if (valid) bx = ((const float4*)boxes)[(size_t)b * NANCH + idx];
    sx1[tid] = bx.x; sy1[tid] = bx.y; sx2[tid] = bx.z; sy2[tid] = bx.w;
    sar[tid] = __fmul_rn(bx.z - bx.x, bx.w - bx.y);
    ssc[tid] = valid ? sc : 0.f;
    skeep[tid] = valid;
  }
  __syncthreads();

  {
    const int wv = tid >> 6, lane = tid & 63;
    float jx1[4], jy1[4], jx2[4], jy2[4], ja[4];
#pragma unroll
    for (int r = 0; r < 4; ++r) {
      int j = (r << 6) | lane;
      jx1[r] = sx1[j]; jy1[r] = sy1[j]; jx2[r] = sx2[j]; jy2[r] = sy2[j];
      ja[r] = sar[j];
    }
    for (int i = wv; i < TOPK; i += 4) {
      const float xi1 = sx1[i], yi1 = sy1[i], xi2 = sx2[i], yi2 = sy2[i];
      const float ai = sar[i];
#pragma unroll
      for (int r = 0; r < 4; ++r) {
        unsigned long long word = 0ull;
        if ((r << 6) + 63 > i) {
          const int j = (r << 6) | lane;
          bool s = false;
          if (j > i && j < TOPK) {
            float xx1 = fmaxf(xi1, jx1[r]);
            float yy1 = fmaxf(yi1, jy1[r]);
            float xx2 = fminf(xi2, jx2[r]);
            float yy2 = fminf(yi2, jy2[r]);
            float iw = fmaxf(0.f, __fsub_rn(xx2, xx1));
            float ih = fmaxf(0.f, __fsub_rn(yy2, yy1));
            float inter = __fmul_rn(iw, ih);
            float denom = __fsub_rn(__fadd_rn(ai, ja[r]), inter);
            float q = __fmul_rn(inter, __builtin_amdgcn_rcpf(denom));
            s = q > 0.5f;
            if (fabsf(q - 0.5f) < 1e-5f)
              s = __fdiv_rn(inter, denom) > 0.5f;
          }
          word = __ballot(s);
        }
        if (lane == 0) sup[i][r] = word;
      }
    }
  }
  __syncthreads();

  if (tid < 64) {
    unsigned long long k0 = __ballot(skeep[tid] != 0);
    unsigned long long k1 = __ballot(skeep[64 + tid] != 0);
    unsigned long long k2 = __ballot(skeep[128 + tid] != 0);
    unsigned long long k3 = __ballot(skeep[192 + tid] != 0);
#define NMS_SCAN_WORD(KW, BASE, CNT)                                     \
    _Pragma("unroll 8")                                                  \
    for (int li = 0; li < (CNT); ++li) {                                 \
      const ulonglong2* s2p =                                            \
          reinterpret_cast<const ulonglong2*>(&sup[(BASE) + li][0]);     \
      ulonglong2 sa = s2p[0];                                            \
      ulonglong2 sb = s2p[1];                                            \
      unsigned long long m = 0ull - ((KW >> li) & 1ull);                 \
      k0 &= ~(sa.x & m); k1 &= ~(sa.y & m);                              \
      k2 &= ~(sb.x & m); k3 &= ~(sb.y & m);                              \
    }
    NMS_SCAN_WORD(k0, 0, 64)
    NMS_SCAN_WORD(k1, 64, 64)
    NMS_SCAN_WORD(k2, 128, 64)
    NMS_SCAN_WORD(k3, 192, 8)
#undef NMS_SCAN_WORD
    skeep[tid]        = (int)((k0 >> tid) & 1ull);
    skeep[64 + tid]   = (int)((k1 >> tid) & 1ull);
    skeep[128 + tid]  = (int)((k2 >> tid) & 1ull);
    skeep[192 + tid]  = (int)((k3 >> tid) & 1ull);
  }
  __syncthreads();

  const size_t base = (size_t)bc * (TOPK * 6);
  for (int f = tid; f < TOPK * 6; f += NTHR) {
    int k = f / 6, comp = f - k * 6;
    float v = 0.f;
    if (skeep[k]) {
      switch (comp) {
        case 0: v = sx1[k]; break;
        case 1: v = sy1[k]; break;
        case 2: v = sx2[k]; break;
        case 3: v = sy2[k]; break;
        case 4: v = ssc[k]; break;
        default: v = (float)c; break;
      }
    }
    out[base + f] = v;
  }
}

// ---------------------------------------------------------------------------
extern "C" void kernel_launch(void* const* d_in, const int* in_sizes, int n_in,
                              void* d_out, int out_size, void* d_ws, size_t ws_size,
                              hipStream_t stream) {
  (void)in_sizes; (void)n_in; (void)out_size;
  const float* boxes  = (const float*)d_in[0];
  const float* scores = (const float*)d_in[1];
  float* out = (float*)d_out;

  const size_t need_ts = (size_t)B_IMG * NCLS * NANCH * sizeof(float);             // 44.4 MB
  const size_t need_tk = (size_t)B_IMG * NCLS * NPART * TOPK * sizeof(uint64_t);   // 4.1 MB
  const size_t need_sb = (size_t)B_IMG * NCLS * 256 * sizeof(float4);              // 2.6 MB
  const size_t need_sk = (size_t)B_IMG * NCLS * 256 * sizeof(uint64_t);            // 1.3 MB

  if (ws_size >= need_ts + need_tk + need_sb + need_sk) {
    char* w = (char*)d_ws;
    float* ts                     = (float*)w;                      w += need_ts;
    unsigned long long* topkeys   = (unsigned long long*)w;         w += need_tk;
    float4* stagedBox             = (float4*)w;                     w += need_sb;
    unsigned long long* stagedKey = (unsigned long long*)w;
    dim3 tgrid((NANCH + 63) / 64, B_IMG);
    transpose_scores_k<<<tgrid, NTHR, 0, stream>>>(scores, ts);
    stage1_k<<<B_IMG * NCLS * NPART, NTHR, 0, stream>>>(scores, ts, 1, topkeys);
    stage2a_k<<<B_IMG * NCLS, NTHR, 0, stream>>>(boxes, topkeys, stagedBox, stagedKey);
    stage2b_k<<<B_IMG * NCLS, 512, 0, stream>>>(stagedBox, stagedKey, out);
  } else if (ws_size >= need_ts + need_tk) {
    float* ts = (float*)d_ws;
    unsigned long long* topkeys = (unsigned long long*)((char*)d_ws + need_ts);
    dim3 tgrid((NANCH + 63) / 64, B_IMG);
    transpose_scores_k<<<tgrid, NTHR, 0, stream>>>(scores, ts);
    stage1_k<<<B_IMG * NCLS * NPART, NTHR, 0, stream>>>(scores, ts, 1, topkeys);
    stage2_full_k<<<B_IMG * NCLS, NTHR, 0, stream>>>(boxes, topkeys, out);
  } else {
    unsigned long long* topkeys = (unsigned long long*)d_ws;
    stage1_k<<<B_IMG * NCLS * NPART, NTHR, 0, stream>>>(scores, (const float*)0, 0, topkeys);
    stage2_full_k<<<B_IMG * NCLS, NTHR, 0, stream>>>(boxes, topkeys, out);
  }
}

// Round 6
// 95.955 us; speedup vs baseline: 1.2746x; 1.1566x over previous
//
#include <hip/hip_runtime.h>
#include <stdint.h>

#define B_IMG  8
#define NANCH  17328          // A*HW = 3*5776
#define NCLS   80
#define TOPK   200
#define NTHR   256
#define NCHUNK 68             // ceil(NANCH/256)
#define CAND_CAP 2560         // per-(b,c) candidate buffer (E=1733, 21 sigma)
#define STAGE_CAP 3072        // per-block LDS staging (E=2048, 24 sigma)
#define THRESH_HI 0.9f

// ---------------------------------------------------------------------------
// helpers (proven in rounds 1-5)
// ---------------------------------------------------------------------------
__device__ __forceinline__ void hist_add(float s, unsigned int* hist) {
  if (s > 0.5f) {
    unsigned int bin = (__float_as_uint(s) - 0x3F000000u) >> 15;
    if (bin > 255u) bin = 255u;
    atomicAdd(&hist[bin], 1u);
  }
}

// ---------------------------------------------------------------------------
// K0: zero the per-(b,c) candidate counters (ws not re-poisoned between runs)
// ---------------------------------------------------------------------------
__global__ void init_k(unsigned int* __restrict__ cnt) {
  int i = blockIdx.x * 256 + threadIdx.x;
  if (i < B_IMG * NCLS) cnt[i] = 0u;
}

// ---------------------------------------------------------------------------
// K1: single coalesced pass over scores; scatter s>0.9 candidates into
// per-(b,c) global buffers. Ballot-aggregated LDS staging, one global-atomic
// batch per block. Overflow/underflow -> cnt poisoned -> stage1 fallback.
// ---------------------------------------------------------------------------
__global__ __launch_bounds__(NTHR) void scatter_k(
    const float* __restrict__ scores,
    unsigned int* __restrict__ cnt,           // [B*NCLS]
    unsigned long long* __restrict__ cand) {  // [B*NCLS][CAND_CAP]
  const int chunk = blockIdx.x;
  const int b = blockIdx.y;
  const int tid = threadIdx.x;
  const int lane = tid & 63;
  const int n = chunk * NTHR + tid;

  __shared__ unsigned int lcnt[NCLS];         // per-class count in this block
  __shared__ unsigned int gb[NCLS];           // per-class global base
  __shared__ unsigned long long skey[STAGE_CAP];
  __shared__ unsigned int smeta[STAGE_CAP];   // (c<<12) | slot
  __shared__ unsigned int s_ns;
  __shared__ unsigned int s_ovf;

  for (int j = tid; j < NCLS; j += NTHR) lcnt[j] = 0u;
  if (tid == 0) { s_ns = 0u; s_ovf = 0u; }
  __syncthreads();

  const float4* row = (const float4*)(scores + ((size_t)b * NANCH +
                        (size_t)(n < NANCH ? n : 0)) * NCLS);
  const unsigned long long lt = (1ull << lane) - 1ull;

  for (int cg = 0; cg < NCLS / 4; ++cg) {
    float4 v = make_float4(0.f, 0.f, 0.f, 0.f);
    if (n < NANCH) v = row[cg];
    float se[4] = {v.x, v.y, v.z, v.w};
#pragma unroll
    for (int e = 0; e < 4; ++e) {
      bool cand_l = (n < NANCH) && (se[e] > THRESH_HI);
      unsigned long long bal = __ballot(cand_l);
      if (bal) {
        const int c = 4 * cg + e;
        unsigned int nw = (unsigned int)__popcll(bal);
        unsigned int slot0 = 0u, pos0 = 0u;
        if (lane == 0) {
          slot0 = atomicAdd(&lcnt[c], nw);
          pos0  = atomicAdd(&s_ns, nw);
        }
        slot0 = (unsigned int)__shfl((int)slot0, 0, 64);
        pos0  = (unsigned int)__shfl((int)pos0, 0, 64);
        if (cand_l) {
          unsigned int r = (unsigned int)__popcll(bal & lt);
          unsigned int pos = pos0 + r;
          if (pos < STAGE_CAP) {
            skey[pos] = ((unsigned long long)__float_as_uint(se[e]) << 32) |
                        (unsigned long long)(0xFFFFFFFFu - (unsigned int)n);
            smeta[pos] = ((unsigned int)c << 12) | (slot0 + r);
          } else {
            s_ovf = 1u;   // benign race: only ever set to 1
          }
        }
      }
    }
  }
  __syncthreads();

  // allocate global ranges per class; poison on staging overflow
  if (tid < NCLS) {
    unsigned int cc = lcnt[tid];
    unsigned int base = 0u;
    const int bc = b * NCLS + tid;
    if (cc) base = atomicAdd(&cnt[bc], cc);
    if (s_ovf) atomicAdd(&cnt[bc], (unsigned int)CAND_CAP + 1u);
    gb[tid] = base;
  }
  __syncthreads();

  unsigned int ns = s_ns; if (ns > STAGE_CAP) ns = STAGE_CAP;
  for (unsigned int j = tid; j < ns; j += NTHR) {
    unsigned int meta = smeta[j];
    int c = (int)(meta >> 12);
    unsigned int slot = meta & 4095u;
    unsigned int pos = gb[c] + slot;
    if (pos < CAND_CAP)
      cand[(size_t)(b * NCLS + c) * CAND_CAP + pos] = skey[j];
    // else dropped: cnt[bc] > CAND_CAP guarantees stage1 fallback
  }
}

// ---------------------------------------------------------------------------
// K2: per-(b,c): exact top-200 (hist cutoff + bitonic sort) from candidate
// buffer; strided full-scan fallback if count out of range. Gathers boxes,
// writes staged (box4, key) records.
// ---------------------------------------------------------------------------
__global__ __launch_bounds__(NTHR) void stage1_k(
    const float* __restrict__ scores, const float* __restrict__ boxes,
    const unsigned int* __restrict__ cnt, const unsigned long long* __restrict__ cand,
    float4* __restrict__ stagedBox, unsigned long long* __restrict__ stagedKey) {
  const int bc = blockIdx.x;
  const int b = bc / NCLS;
  const int c = bc - b * NCLS;
  const int tid = threadIdx.x;

  __shared__ unsigned long long ck[CAND_CAP];   // 20 KB
  __shared__ unsigned long long selk[512];
  __shared__ unsigned int hist[256];
  __shared__ unsigned int sh_cutbits;
  __shared__ int sh_m;

  for (int j = tid; j < 256; j += NTHR) hist[j] = 0u;
  if (tid == 0) sh_m = 0;
  __syncthreads();

  const unsigned int m = cnt[bc];

  if (m >= TOPK && m <= CAND_CAP) {
    // ---------------- fast path: candidates hold the exact top-200 ----------
    const unsigned long long* cb = cand + (size_t)bc * CAND_CAP;
    for (unsigned int j = tid; j < m; j += NTHR) ck[j] = cb[j];
    __syncthreads();
    for (unsigned int j = tid; j < m; j += NTHR) {
      unsigned int sb = (unsigned int)(ck[j] >> 32);
      unsigned int bin = (sb - 0x3F000000u) >> 15;
      if (bin > 255u) bin = 255u;
      atomicAdd(&hist[bin], 1u);
    }
    __syncthreads();

    if (tid < 64) {
      int base = 255 - 4 * tid;
      int s4 = (int)(hist[base] + hist[base - 1] + hist[base - 2] + hist[base - 3]);
      int cum = s4;
      for (int d = 1; d < 64; d <<= 1) {
        int o = __shfl_up(cum, d, 64);
        if (tid >= d) cum += o;
      }
      unsigned long long bal = __ballot(cum >= TOPK);
      if (bal == 0ull) {
        if (tid == 0) sh_cutbits = 0x3F000000u;
      } else {
        int l0 = __builtin_ctzll(bal);
        if (tid == l0) {
          unsigned int acc = (unsigned int)(cum - s4);
          int cutbin = base - 3;
          for (int k = 0; k < 4; ++k) {
            acc += hist[base - k];
            if (acc >= TOPK) { cutbin = base - k; break; }
          }
          sh_cutbits = 0x3F000000u + ((unsigned int)cutbin << 15);
        }
      }
    }
    __syncthreads();
    const unsigned int cutbits = sh_cutbits;

    for (unsigned int j = tid; j < m; j += NTHR) {
      unsigned long long k = ck[j];
      if ((unsigned int)(k >> 32) >= cutbits) {
        int slot = atomicAdd(&sh_m, 1);
        if (slot < 512) selk[slot] = k;
      }
    }
    __syncthreads();
  } else {
    // ---------------- fallback: strided 2-pass (proven rd1 code) ------------
    const float* src = scores + (size_t)b * NANCH * NCLS + c;
    for (int i = tid; i < NANCH; i += NTHR) hist_add(src[(size_t)i * NCLS], hist);
    __syncthreads();

    if (tid == 0) {
      unsigned int acc = 0;
      int cut = 0;
      for (int bin = 255; bin >= 0; --bin) {
        acc += hist[bin];
        if (acc >= TOPK) { cut = bin; break; }
      }
      sh_cutbits = 0x3F000000u + ((unsigned int)cut << 15);
    }
    __syncthreads();
    const unsigned int cutbits = sh_cutbits;

    for (int i = tid; i < NANCH; i += NTHR) {
      float s = src[(size_t)i * NCLS];
      if (s > 0.5f && __float_as_uint(s) >= cutbits) {
        int slot = atomicAdd(&sh_m, 1);
        if (slot < 512)
          selk[slot] = ((unsigned long long)__float_as_uint(s) << 32) |
                       (unsigned long long)(0xFFFFFFFFu - (unsigned int)i);
      }
    }
    __syncthreads();
  }

  int M = sh_m; if (M > 512) M = 512;
  const int S = (M <= 256) ? 256 : 512;
  for (int j = M + tid; j < S; j += NTHR) selk[j] = 0ull;

  // ---- bitonic sort S elements, descending (proven) ----
  for (int size = 2; size <= S; size <<= 1) {
    for (int st = size >> 1; st > 0; st >>= 1) {
      __syncthreads();
      for (int t = tid; t < (S >> 1); t += NTHR) {
        int lo = 2 * t - (t & (st - 1));
        int hi = lo + st;
        bool desc = ((lo & size) == 0);
        unsigned long long a = selk[lo], bb = selk[hi];
        if ((a < bb) == desc) { selk[lo] = bb; selk[hi] = a; }
      }
    }
  }
  __syncthreads();

  // ---- gather boxes + write staged records ----
  {
    unsigned long long key = selk[tid];
    int valid = (tid < TOPK) && (key != 0ull);
    unsigned int idx = 0xFFFFFFFFu - (unsigned int)(key & 0xFFFFFFFFull);
    float4 bx = make_float4(0.f, 0.f, 0.f, 0.f);
    if (valid) bx = ((const float4*)boxes)[(size_t)b * NANCH + idx];
    stagedBox[(size_t)bc * 256 + tid] = bx;
    stagedKey[(size_t)bc * 256 + tid] = key;
  }
}

// ---------------------------------------------------------------------------
// K3: suppression-matrix build -> global sup words. 2 blocks per (b,c),
// rows interleaved i = 2*(4k+wv)+h. Guard-band IEEE div is branch-skipped.
// ---------------------------------------------------------------------------
__global__ __launch_bounds__(NTHR) void supbuild_k(
    const float4* __restrict__ stagedBox, const unsigned long long* __restrict__ stagedKey,
    unsigned long long* __restrict__ supg) {   // [B*NCLS][TOPK][4]
  const int blk = blockIdx.x;
  const int h = blk & 1;
  const int bc = blk >> 1;
  const int tid = threadIdx.x;
  const int wv = tid >> 6, lane = tid & 63;

  __shared__ float sx1[256], sy1[256], sx2[256], sy2[256], sar[256];

  if (tid < 256) {
    float4 bx = stagedBox[(size_t)bc * 256 + tid];
    sx1[tid] = bx.x; sy1[tid] = bx.y; sx2[tid] = bx.z; sy2[tid] = bx.w;
    sar[tid] = __fmul_rn(bx.z - bx.x, bx.w - bx.y);   // _rn: block FMA contraction
  }
  __syncthreads();

  float jx1[4], jy1[4], jx2[4], jy2[4], ja[4];
#pragma unroll
  for (int r = 0; r < 4; ++r) {
    int j = (r << 6) | lane;
    jx1[r] = sx1[j]; jy1[r] = sy1[j]; jx2[r] = sx2[j]; jy2[r] = sy2[j];
    ja[r] = sar[j];
  }

  for (int k = 0; k < 25; ++k) {
    const int i = 2 * (4 * k + wv) + h;    // covers 0..199 over the block pair
    const float xi1 = sx1[i], yi1 = sy1[i], xi2 = sx2[i], yi2 = sy2[i];
    const float ai = sar[i];
    unsigned long long w[4];
#pragma unroll
    for (int r = 0; r < 4; ++r) {
      unsigned long long word = 0ull;
      if ((r << 6) + 63 > i) {             // wave-uniform
        const int j = (r << 6) | lane;
        const bool vp = (j > i) && (j < TOPK);
        float xx1 = fmaxf(xi1, jx1[r]);
        float yy1 = fmaxf(yi1, jy1[r]);
        float xx2 = fminf(xi2, jx2[r]);
        float yy2 = fminf(yi2, jy2[r]);
        float iw = fmaxf(0.f, __fsub_rn(xx2, xx1));
        float ih = fmaxf(0.f, __fsub_rn(yy2, yy1));
        float inter = __fmul_rn(iw, ih);
        float denom = __fsub_rn(__fadd_rn(ai, ja[r]), inter);
        float q = __fmul_rn(inter, __builtin_amdgcn_rcpf(denom));
        bool s = vp && (q > 0.5f);
        bool gbad = vp && (fabsf(q - 0.5f) < 1e-5f);
        if (__ballot(gbad)) {              // ~never: exact IEEE div, XLA-bitwise
          if (gbad) s = __fdiv_rn(inter, denom) > 0.5f;
        }
        word = __ballot(s);
      }
      w[r] = word;
    }
    if (lane == 0) {
      ulonglong2* dst = (ulonglong2*)(supg + ((size_t)bc * TOPK + i) * 4);
      ulonglong2 t0; t0.x = w[0]; t0.y = w[1];
      ulonglong2 t1; t1.x = w[2]; t1.y = w[3];
      dst[0] = t0; dst[1] = t1;
    }
  }
}

// ---------------------------------------------------------------------------
// K4: serial bit-scan (wave 0) + emit via LDS-staged float4 stores
// ---------------------------------------------------------------------------
__global__ __launch_bounds__(NTHR) void scanemit_k(
    const float4* __restrict__ stagedBox, const unsigned long long* __restrict__ stagedKey,
    const unsigned long long* __restrict__ supg, float* __restrict__ out) {
  const int bc = blockIdx.x;
  const int c = bc - (bc / NCLS) * NCLS;
  const int tid = threadIdx.x;

  __shared__ float sx1[256], sy1[256], sx2[256], sy2[256], ssc[256];
  __shared__ int skeep[256];
  __shared__ __align__(16) unsigned long long sup[TOPK][4];   // 6.4 KB
  __shared__ __align__(16) float eout[TOPK * 6];

  {
    unsigned long long key = stagedKey[(size_t)bc * 256 + tid];
    float4 bx = stagedBox[(size_t)bc * 256 + tid];
    int valid = (tid < TOPK) && (key != 0ull);
    sx1[tid] = bx.x; sy1[tid] = bx.y; sx2[tid] = bx.z; sy2[tid] = bx.w;
    ssc[tid] = valid ? __uint_as_float((unsigned int)(key >> 32)) : 0.f;
    skeep[tid] = valid;
  }
  // coalesced sup load: 400 x ulonglong2
  {
    const ulonglong2* src = (const ulonglong2*)(supg + (size_t)bc * TOPK * 4);
    ulonglong2* dst = (ulonglong2*)&sup[0][0];
    for (int f = tid; f < TOPK * 2; f += NTHR) dst[f] = src[f];
  }
  __syncthreads();

  // ---- serial scan: pure bit-ops, keep state in 4 u64 regs (wave 0) -------
  if (tid < 64) {
    unsigned long long k0 = __ballot(skeep[tid] != 0);
    unsigned long long k1 = __ballot(skeep[64 + tid] != 0);
    unsigned long long k2 = __ballot(skeep[128 + tid] != 0);
    unsigned long long k3 = __ballot(skeep[192 + tid] != 0);  // 200..255 are 0
#define NMS_SCAN_WORD(KW, BASE, CNT)                                     \
    _Pragma("unroll 8")                                                  \
    for (int li = 0; li < (CNT); ++li) {                                 \
      const ulonglong2* s2p =                                            \
          reinterpret_cast<const ulonglong2*>(&sup[(BASE) + li][0]);     \
      ulonglong2 sa = s2p[0];                                            \
      ulonglong2 sb = s2p[1];                                            \
      unsigned long long m = 0ull - ((KW >> li) & 1ull);                 \
      k0 &= ~(sa.x & m); k1 &= ~(sa.y & m);                              \
      k2 &= ~(sb.x & m); k3 &= ~(sb.y & m);                              \
    }
    NMS_SCAN_WORD(k0, 0, 64)
    NMS_SCAN_WORD(k1, 64, 64)
    NMS_SCAN_WORD(k2, 128, 64)
    NMS_SCAN_WORD(k3, 192, 8)
#undef NMS_SCAN_WORD
    skeep[tid]        = (int)((k0 >> tid) & 1ull);
    skeep[64 + tid]   = (int)((k1 >> tid) & 1ull);
    skeep[128 + tid]  = (int)((k2 >> tid) & 1ull);
    skeep[192 + tid]  = (int)((k3 >> tid) & 1ull);
  }
  __syncthreads();

  // ---- emit via LDS stage, then 300 coalesced float4 stores ---------------
  if (tid < TOPK) {
    int kp = skeep[tid];
    eout[tid * 6 + 0] = kp ? sx1[tid] : 0.f;
    eout[tid * 6 + 1] = kp ? sy1[tid] : 0.f;
    eout[tid * 6 + 2] = kp ? sx2[tid] : 0.f;
    eout[tid * 6 + 3] = kp ? sy2[tid] : 0.f;
    eout[tid * 6 + 4] = kp ? ssc[tid] : 0.f;
    eout[tid * 6 + 5] = kp ? (float)c : 0.f;
  }
  __syncthreads();

  float4* out4 = (float4*)(out + (size_t)bc * (TOPK * 6));
  const float4* e4 = (const float4*)eout;
  for (int f = tid; f < (TOPK * 6) / 4; f += NTHR) out4[f] = e4[f];
}

// ---------------------------------------------------------------------------
// Fallback: proven monolithic kernel (strided reads), used only if ws tiny
// ---------------------------------------------------------------------------
__global__ __launch_bounds__(NTHR) void select_nms_k(
    const float* __restrict__ boxes, const float* __restrict__ scores,
    float* __restrict__ out) {
  const int blk = blockIdx.x;
  const int b = blk / NCLS;
  const int c = blk - b * NCLS;
  const int tid = threadIdx.x;

  __shared__ unsigned int hist[256];
  __shared__ unsigned long long keys[1024];
  __shared__ float sx1[TOPK], sy1[TOPK], sx2[TOPK], sy2[TOPK], sar[TOPK], ssc[TOPK];
  __shared__ int skeep[TOPK];
  __shared__ unsigned int sh_cutbits;
  __shared__ int sh_m;

  const float* src = scores + (size_t)b * NANCH * NCLS + c;

  for (int j = tid; j < 256; j += NTHR) hist[j] = 0;
  if (tid == 0) sh_m = 0;
  __syncthreads();

  for (int i = tid; i < NANCH; i += NTHR) hist_add(src[(size_t)i * NCLS], hist);
  __syncthreads();

  if (tid == 0) {
    unsigned int acc = 0;
    int cut = 0;
    for (int bin = 255; bin >= 0; --bin) {
      acc += hist[bin];
      if (acc >= TOPK) { cut = bin; break; }
    }
    sh_cutbits = 0x3F000000u + ((unsigned int)cut << 15);
  }
  __syncthreads();
  const unsigned int cutbits = sh_cutbits;

  for (int i = tid; i < NANCH; i += NTHR) {
    float s = src[(size_t)i * NCLS];
    if (s > 0.5f && __float_as_uint(s) >= cutbits) {
      int slot = atomicAdd(&sh_m, 1);
      if (slot < 1024)
        keys[slot] = ((unsigned long long)__float_as_uint(s) << 32) |
                     (unsigned long long)(0xFFFFFFFFu - (unsigned int)i);
    }
  }
  __syncthreads();
  int M = sh_m; if (M > 1024) M = 1024;
  for (int j = M + tid; j < 1024; j += NTHR) keys[j] = 0ull;

  for (int size = 2; size <= 1024; size <<= 1) {
    for (int st = size >> 1; st > 0; st >>= 1) {
      __syncthreads();
      for (int t = tid; t < 512; t += NTHR) {
        int lo = 2 * t - (t & (st - 1));
        int hi = lo + st;
        bool desc = ((lo & size) == 0);
        unsigned long long a = keys[lo], bb = keys[hi];
        if ((a < bb) == desc) { keys[lo] = bb; keys[hi] = a; }
      }
    }
  }
  __syncthreads();

  if (tid < TOPK) {
    unsigned long long key = keys[tid];
    int valid = (key != 0ull);
    float sc = __uint_as_float((unsigned int)(key >> 32));
    unsigned int idx = 0xFFFFFFFFu - (unsigned int)(key & 0xFFFFFFFFull);
    float4 bx = make_float4(0.f, 0.f, 0.f, 0.f);
    if (valid) bx = ((const float4*)boxes)[(size_t)b * NANCH + idx];
    sx1[tid] = bx.x; sy1[tid] = bx.y; sx2[tid] = bx.z; sy2[tid] = bx.w;
    sar[tid] = __fmul_rn(bx.z - bx.x, bx.w - bx.y);
    ssc[tid] = valid ? sc : 0.f;
    skeep[tid] = valid;
  }
  __syncthreads();

  if (tid < 64) {
    const int lane = tid;
    float x1v[4], y1v[4], x2v[4], y2v[4], av[4];
    int km = 0;
#pragma unroll
    for (int r = 0; r < 4; ++r) {
      int j = lane + (r << 6);
      if (j < TOPK) {
        x1v[r] = sx1[j]; y1v[r] = sy1[j]; x2v[r] = sx2[j]; y2v[r] = sy2[j];
        av[r] = sar[j];
        if (skeep[j]) km |= (1 << r);
      } else {
        x1v[r] = 0.f; y1v[r] = 0.f; x2v[r] = 0.f; y2v[r] = 0.f; av[r] = 0.f;
      }
    }
#pragma unroll
    for (int ri = 0; ri < 4; ++ri) {
      const int imax = (ri == 3) ? (TOPK - 192) : 64;
      for (int li = 0; li < imax; ++li) {
        const int i = (ri << 6) + li;
        int kmi = __shfl(km, li, 64);
        if (!((kmi >> ri) & 1)) continue;
        float xi1 = __shfl(x1v[ri], li, 64);
        float yi1 = __shfl(y1v[ri], li, 64);
        float xi2 = __shfl(x2v[ri], li, 64);
        float yi2 = __shfl(y2v[ri], li, 64);
        float ai  = __shfl(av[ri],  li, 64);
#pragma unroll
        for (int r = 0; r < 4; ++r) {
          int j = lane + (r << 6);
          if (j > i && j < TOPK && ((km >> r) & 1)) {
            float xx1 = fmaxf(xi1, x1v[r]);
            float yy1 = fmaxf(yi1, y1v[r]);
            float xx2 = fminf(xi2, x2v[r]);
            float yy2 = fminf(yi2, y2v[r]);
            float iw = fmaxf(0.f, __fsub_rn(xx2, xx1));
            float ih = fmaxf(0.f, __fsub_rn(yy2, yy1));
            float inter = __fmul_rn(iw, ih);
            float denom = __fsub_rn(__fadd_rn(ai, av[r]), inter);
            float iou = __fdiv_rn(inter, denom);
            if (iou > 0.5f) km &= ~(1 << r);
          }
        }
      }
    }
#pragma unroll
    for (int r = 0; r < 4; ++r) {
      int j = lane + (r << 6);
      if (j < TOPK) skeep[j] = (km >> r) & 1;
    }
  }
  __syncthreads();

  const size_t base = ((size_t)b * NCLS + c) * (TOPK * 6);
  for (int f = tid; f < TOPK * 6; f += NTHR) {
    int k = f / 6, comp = f - k * 6;
    float v = 0.f;
    if (skeep[k]) {
      switch (comp) {
        case 0: v = sx1[k]; break;
        case 1: v = sy1[k]; break;
        case 2: v = sx2[k]; break;
        case 3: v = sy2[k]; break;
        case 4: v = ssc[k]; break;
        default: v = (float)c; break;
      }
    }
    out[base + f] = v;
  }
}

// ---------------------------------------------------------------------------
extern "C" void kernel_launch(void* const* d_in, const int* in_sizes, int n_in,
                              void* d_out, int out_size, void* d_ws, size_t ws_size,
                              hipStream_t stream) {
  (void)in_sizes; (void)n_in; (void)out_size;
  const float* boxes  = (const float*)d_in[0];
  const float* scores = (const float*)d_in[1];
  float* out = (float*)d_out;

  const int NBC = B_IMG * NCLS;                                   // 640
  const size_t need_cnt = 4096;                                   // 640*4 rounded
  const size_t need_cd  = (size_t)NBC * CAND_CAP * sizeof(uint64_t);   // 13.1 MB
  const size_t need_sb  = (size_t)NBC * 256 * sizeof(float4);          // 2.6 MB
  const size_t need_sk  = (size_t)NBC * 256 * sizeof(uint64_t);        // 1.3 MB
  const size_t need_sp  = (size_t)NBC * TOPK * 4 * sizeof(uint64_t);   // 4.1 MB
  const size_t need = need_cnt + need_cd + need_sb + need_sk + need_sp; // ~21 MB

  if (ws_size >= need) {
    char* w = (char*)d_ws;
    unsigned int* cnt             = (unsigned int*)w;          w += need_cnt;
    unsigned long long* cand      = (unsigned long long*)w;    w += need_cd;
    float4* stagedBox             = (float4*)w;                w += need_sb;
    unsigned long long* stagedKey = (unsigned long long*)w;    w += need_sk;
    unsigned long long* supg      = (unsigned long long*)w;

    init_k<<<(NBC + 255) / 256, 256, 0, stream>>>(cnt);
    scatter_k<<<dim3(NCHUNK, B_IMG), NTHR, 0, stream>>>(scores, cnt, cand);
    stage1_k<<<NBC, NTHR, 0, stream>>>(scores, boxes, cnt, cand, stagedBox, stagedKey);
    supbuild_k<<<NBC * 2, NTHR, 0, stream>>>(stagedBox, stagedKey, supg);
    scanemit_k<<<NBC, NTHR, 0, stream>>>(stagedBox, stagedKey, supg, out);
  } else {
    select_nms_k<<<NBC, NTHR, 0, stream>>>(boxes, scores, out);
  }
}